// Round 12
// baseline (392.118 us; speedup 1.0000x reference)
//
#include <hip/hip_runtime.h>
#include <math.h>

#define H 1024
#define W 1024
#define HW (H * W)

typedef _Float16 half8 __attribute__((ext_vector_type(8)));
typedef _Float16 half4 __attribute__((ext_vector_type(4)));
typedef _Float16 h2 __attribute__((ext_vector_type(2)));
typedef float f32x4 __attribute__((ext_vector_type(4)));
typedef unsigned uint4v __attribute__((ext_vector_type(4)));

__device__ __forceinline__ float fast_sqrtf(float x) { return __builtin_amdgcn_sqrtf(x); }
__device__ __forceinline__ float fast_expf(float x) { return __builtin_amdgcn_exp2f(x * 1.44269504088896340736f); }

__device__ __forceinline__ h2 pkrtz(float a, float b) {
    return __builtin_bit_cast(h2, __builtin_amdgcn_cvt_pkrtz(a, b));
}

// ---------------- stats pass 1: partial sum/sumsq per (b,c) chunk ----------------
__global__ __launch_bounds__(256) void stats_partial(const float* __restrict__ x,
                                                     double* __restrict__ part) {
    int blk = blockIdx.x;
    int bc = blk >> 5;
    int j = blk & 31;
    const float* p = x + (size_t)bc * HW + (size_t)j * (HW / 32);
    int tid = threadIdx.x;
    double s = 0.0, q = 0.0;
    const float4* p4 = (const float4*)p;
    for (int i = tid; i < (HW / 32) / 4; i += 256) {
        float4 v = p4[i];
        s += (double)v.x + (double)v.y + (double)v.z + (double)v.w;
        q += (double)v.x * v.x + (double)v.y * v.y + (double)v.z * v.z + (double)v.w * v.w;
    }
    __shared__ double ls[256], lq[256];
    ls[tid] = s;
    lq[tid] = q;
    __syncthreads();
    for (int ofs = 128; ofs > 0; ofs >>= 1) {
        if (tid < ofs) { ls[tid] += ls[tid + ofs]; lq[tid] += lq[tid + ofs]; }
        __syncthreads();
    }
    if (tid == 0) {
        part[blk * 2] = ls[0];
        part[blk * 2 + 1] = lq[0];
    }
}

// ---------------- stats pass 2 + weight prep (h-only conv weights) ----------------
__global__ __launch_bounds__(256) void stats_final_prep(const double* __restrict__ part,
                                                        const float* __restrict__ chw,
                                                        const float* __restrict__ w1,
                                                        const float* __restrict__ w2,
                                                        const float* __restrict__ w3,
                                                        float* __restrict__ stats,
                                                        _Float16* __restrict__ w1a,
                                                        _Float16* __restrict__ w3f,
                                                        _Float16* __restrict__ w2bh) {
    int tid = threadIdx.x;
    __shared__ float cw[4];
    if (tid == 0) {
        float m = fmaxf(fmaxf(chw[0], chw[1]), fmaxf(chw[2], chw[3]));
        float e0 = expf(chw[0] - m), e1 = expf(chw[1] - m);
        float e2 = expf(chw[2] - m), e3 = expf(chw[3] - m);
        float s = e0 + e1 + e2 + e3;
        cw[0] = e0 / s; cw[1] = e1 / s; cw[2] = e2 / s; cw[3] = e3 / s;
    }
    __syncthreads();
    if (tid < 16) {
        double s = 0.0, q = 0.0;
        for (int j = 0; j < 32; j++) {
            s += part[(tid * 32 + j) * 2];
            q += part[(tid * 32 + j) * 2 + 1];
        }
        double n = (double)HW;
        double var = (q - s * s / n) / (n - 1.0);
        if (var < 0) var = 0;
        float gs = (float)sqrt(var);
        int c = tid & 3;
        float gf = fminf(fmaxf(gs * 5.0f, 0.5f), 2.0f);
        float cf = fminf(fmaxf(gs * cw[c] * 2.0f, 0.8f), 1.2f);
        stats[tid * 2] = 0.05f * gf * cf;
        stats[tid * 2 + 1] = 0.20f * gf * cf;
    }
    // conv1 A-frags, h-only: 4 sets (c,h) of 64 lanes x 8
    for (int i = tid; i < 256; i += 256) {
        int s = i >> 6, l = i & 63;
        int c = s >> 1, h = s & 1;
        int m = l & 15, cg = l >> 4;
        int co = h * 16 + m;
#pragma unroll
        for (int j = 0; j < 8; j++) {
            int k = c * 32 + cg * 8 + j;
            float v = 0.f;
            if (k < 36) {
                int t = k >> 2, ci = k & 3;
                v = w1[(co * 4 + ci) * 9 + t];
            }
            w1a[i * 8 + j] = (_Float16)v;
        }
    }
    for (int idx = tid; idx < 576; idx += 256) {           // conv2 B-frags (h only)
        int t = idx >> 6, l = idx & 63;
        int co = l & 15, cg = l >> 4;
#pragma unroll
        for (int j = 0; j < 8; j++) {
            int ci = cg * 8 + j;
            w2bh[idx * 8 + j] = (_Float16)w2[(co * 32 + ci) * 9 + t];
        }
    }
    for (int idx = tid; idx < 384; idx += 256) {           // conv3 B-frags: 6 sets (ky,grp) h-only
        int t = idx >> 6, l = idx & 63;
        int ky = t / 2, grp = t & 1;
        int co = l & 15, bq = l >> 4;
#pragma unroll
        for (int j = 0; j < 8; j++) {
            int k = bq * 8 + j;
            float v = 0.f;
            if (co < 8) {
                if (grp == 0) {
                    int kxp = k >> 4, ci = k & 15;
                    v = w3[((co * 16 + ci) * 3 + ky) * 3 + kxp];
                } else if (k < 16) {
                    v = w3[((co * 16 + k) * 3 + ky) * 3 + 2];
                }
            }
            w3f[idx * 8 + j] = (_Float16)v;
        }
    }
}

// ---------------- fused conv1+conv2, f16 h-only MFMA ----------------
// v11: x halo staged as channel-pair-packed f16; A-operand from ds_read_b32, no unpack.
__global__ __launch_bounds__(256, 5) void conv12_mfma(const float* __restrict__ x,
                                                      const _Float16* __restrict__ w1a,
                                                      const float* __restrict__ b1,
                                                      const _Float16* __restrict__ wbh,
                                                      const float* __restrict__ b2,
                                                      _Float16* __restrict__ f2n,
                                                      size_t f2n_bstride, int batch0) {
    __shared__ __align__(16) char smem[30656];
    char* f1t = smem;                                  // 10*34*80 = 27200 B (h-only)
    unsigned* xp = (unsigned*)(smem + 27200);          // 2 planes x [12][36] u32 packed f16 pairs
    int tid = threadIdx.x;
    int lane = tid & 63;
    int wid = tid >> 6;
    int bx = blockIdx.x * 32, by = blockIdx.y * 8;
    int n = lane & 15, cg = lane >> 4;
    int m = lane & 15, b = lane >> 4;
    const float* xb = x + (size_t)(batch0 + blockIdx.z) * 4 * HW;
    _Float16* f2nb = f2n + (size_t)blockIdx.z * f2n_bstride;

    // phase 1: stage x halo (rows by-2..by+9, cols bx-2..bx+33) as packed f16 channel pairs
    {
        int idx = tid;
        int r = tid / 36, c = tid - r * 36, plane = 0;
#pragma unroll
        for (int it = 0; it < 4; ++it) {
            if (idx < 864) {
                int gy = by + r - 2, gx = bx + c - 2;
                float v0 = 0.f, v1 = 0.f;
                if ((unsigned)gy < H && (unsigned)gx < W) {
                    const float* pp = xb + (size_t)(2 * plane) * HW + gy * W + gx;
                    v0 = pp[0];
                    v1 = pp[HW];
                }
                xp[idx] = __builtin_bit_cast(unsigned, pkrtz(v0, v1));
            }
            idx += 256;
            c += 4; if (c >= 36) { c -= 36; r += 1; }
            r += 7; if (r >= 12) { r -= 12; plane += 1; }
        }
    }

    half8 Wf00 = *(const half8*)(w1a + (0 * 64 + lane) * 8);
    half8 Wf01 = *(const half8*)(w1a + (1 * 64 + lane) * 8);
    half8 Wf10 = *(const half8*)(w1a + (2 * 64 + lane) * 8);
    half8 Wf11 = *(const half8*)(w1a + (3 * 64 + lane) * 8);
    float bias1[8];
#pragma unroll
    for (int h = 0; h < 2; h++)
#pragma unroll
        for (int j = 0; j < 4; j++)
            bias1[h * 4 + j] = b1[h * 16 + cg * 4 + j];
    half8 Bh[9];
#pragma unroll
    for (int t = 0; t < 9; t++)
        Bh[t] = *(const half8*)(wbh + (t * 64 + lane) * 8);
    f32x4 binit;
#pragma unroll
    for (int j = 0; j < 4; j++) binit[j] = b2[b * 4 + j];

    int t0 = 2 * cg, t1 = 2 * cg + 1;
    int dy0 = (t0 * 11) >> 5, dx0 = t0 - 3 * dy0;
    int dy1 = (t1 * 11) >> 5, dx1 = t1 - 3 * dy1;
    int off0 = dy0 * 36 + dx0, off1 = dy1 * 36 + dx1;
    __syncthreads();

    // phase 2: conv1 via MFMA; 22 tiles of 16 px cover the 340-px halo
#pragma unroll 1
    for (int tt = wid; tt < 22; tt += 4) {
        int p = tt * 16 + n;
        bool valid = p < 340;
        int pc = valid ? p : 339;
        int ry = pc / 34, cx = pc - ry * 34;
        int gy = by + ry - 1, gx = bx + cx - 1;
        bool ok = ((unsigned)gy < H) && ((unsigned)gx < W);
        int base = ry * 36 + cx;
        uint4v uv;
        uv.x = xp[base + off0];
        uv.y = xp[432 + base + off0];
        uv.z = xp[base + off1];
        uv.w = xp[432 + base + off1];
        half8 Xh0 = __builtin_bit_cast(half8, uv);
        half8 Xh1 = {0, 0, 0, 0, 0, 0, 0, 0};
        if (cg == 0) {
            uint4v uw = {0, 0, 0, 0};
            uw.x = xp[base + 74];                      // tap 8 (dy=2,dx=2), ch0|ch1
            uw.y = xp[432 + base + 74];                // ch2|ch3
            Xh1 = __builtin_bit_cast(half8, uw);
        }
        f32x4 d0, d1;
#pragma unroll
        for (int j = 0; j < 4; j++) { d0[j] = bias1[j]; d1[j] = bias1[4 + j]; }
        d0 = __builtin_amdgcn_mfma_f32_16x16x32_f16(Wf00, Xh0, d0, 0, 0, 0);
        d0 = __builtin_amdgcn_mfma_f32_16x16x32_f16(Wf10, Xh1, d0, 0, 0, 0);
        d1 = __builtin_amdgcn_mfma_f32_16x16x32_f16(Wf01, Xh0, d1, 0, 0, 0);
        d1 = __builtin_amdgcn_mfma_f32_16x16x32_f16(Wf11, Xh1, d1, 0, 0, 0);
        if (valid) {
            char* pxb = f1t + ry * 2720 + cx * 80;
#pragma unroll
            for (int h = 0; h < 2; h++) {
                f32x4 d = h ? d1 : d0;
                half4 hq;
#pragma unroll
                for (int j = 0; j < 4; j++) {
                    float v = d[j];
                    v = fmaxf(v, 0.2f * v);
                    v = ok ? v : 0.f;
                    hq[j] = (_Float16)v;
                }
                *(half4*)(pxb + (h * 4 + cg) * 8) = hq;
            }
        }
    }
    __syncthreads();

    // phase 3: conv2 via rolling-row f16 MFMA, D = W*X (lane owns px, 4 co)
    int wx = wid & 1, wy = wid >> 1;
    f32x4 acc2[4];
#pragma unroll
    for (int r = 0; r < 4; r++) acc2[r] = binit;
#pragma unroll
    for (int iy = 0; iy < 6; iy++) {
        int f1row = wy * 4 + iy;
        half8 ah[3];
#pragma unroll
        for (int kx = 0; kx < 3; kx++) {
            int pxi = wx * 16 + m + kx;
            ah[kx] = *(const half8*)(f1t + f1row * 2720 + pxi * 80 + b * 16);
        }
#pragma unroll
        for (int kx = 0; kx < 3; kx++) {
#pragma unroll
            for (int ry = 0; ry < 4; ry++) {
                if (ry >= iy - 2 && ry <= iy) {
                    const int t = (iy - ry) * 3 + kx;
                    acc2[ry] = __builtin_amdgcn_mfma_f32_16x16x32_f16(Bh[t], ah[kx], acc2[ry], 0, 0, 0);
                }
            }
        }
    }

    // epilogue (h-only f2n): leaky -> f16 -> direct store, 32B/px
    int x0 = bx + wx * 16 + m;
    int y0 = by + wy * 4;
    int co_off = b * 4;
#pragma unroll
    for (int ry = 0; ry < 4; ry++) {
        half4 hq;
#pragma unroll
        for (int j = 0; j < 4; j++) {
            float v = acc2[ry][j];
            v = fmaxf(v, 0.2f * v);
            hq[j] = (_Float16)v;
        }
        *(half4*)(f2nb + ((size_t)(y0 + ry) * W + x0) * 16 + co_off) = hq;
    }
}

// ---------------- conv3: h-only f16 MFMA, 32x8 tile, f16 output ----------------
__global__ __launch_bounds__(256) void conv3_mfma(const _Float16* __restrict__ f2n,
                                                  size_t f2n_bstride, int batch0,
                                                  const _Float16* __restrict__ w3f,
                                                  const float* __restrict__ bias,
                                                  _Float16* __restrict__ f3all) {
    __shared__ __align__(16) char st[10 * 34 * 40];    // 13600 B
    int tid = threadIdx.x;
    int lane = tid & 63;
    int wid = tid >> 6;
    int bx = blockIdx.x * 32, by = blockIdx.y * 8;
    const _Float16* f2nb = f2n + (size_t)blockIdx.z * f2n_bstride;
    _Float16* f3 = f3all + (size_t)(batch0 + blockIdx.z) * 8 * HW;

    // stage: rows by-1..by+8, px bx-1..bx+32, 2 x 16B chunks per px (680 tasks)
    for (int idx = tid; idx < 680; idx += 256) {
        int c0 = idx & 1;
        int rp = idx >> 1;
        int r = rp / 34, p = rp - r * 34;
        int gy = by + r - 1, gx = bx + p - 1;
        half8 v = {0, 0, 0, 0, 0, 0, 0, 0};
        if ((unsigned)gy < H && (unsigned)gx < W)
            v = *(const half8*)(f2nb + ((size_t)gy * W + gx) * 16 + c0 * 8);
        *(half8*)(st + r * 1360 + p * 40 + c0 * 16) = v;
    }

    half8 F0[3], F1[3];                                // per ky: grp0-h, grp1-h
#pragma unroll
    for (int ky = 0; ky < 3; ky++) {
        F0[ky] = *(const half8*)(w3f + ((ky * 2 + 0) * 64 + lane) * 8);
        F1[ky] = *(const half8*)(w3f + ((ky * 2 + 1) * 64 + lane) * 8);
    }
    int m = lane & 15, b = lane >> 4;
    int halfco = b & 1, kxp = b >> 1;
    int wx = wid & 1, wy = wid >> 1;
    float bc = (m < 8) ? bias[m] : 0.f;
    f32x4 acc[4];
#pragma unroll
    for (int r = 0; r < 4; r++) acc[r] = (f32x4){bc, bc, bc, bc};
    int pA = wx * 16 + m + kxp;                        // halo-local px for A (kx -1,0)
    int pB = wx * 16 + m + 2;                          // halo-local px for B (kx +1)
    __syncthreads();

#pragma unroll
    for (int iy = 0; iy < 6; iy++) {
        const char* rp = st + (wy * 4 + iy) * 1360;
        half8 ka_h = *(const half8*)(rp + pA * 40 + halfco * 16);
        half8 kb_h = *(const half8*)(rp + pB * 40 + halfco * 16);
#pragma unroll
        for (int ry = 0; ry < 4; ry++) {
            if (ry >= iy - 2 && ry <= iy) {
                const int ky = iy - ry;
                acc[ry] = __builtin_amdgcn_mfma_f32_16x16x32_f16(ka_h, F0[ky], acc[ry], 0, 0, 0);
                acc[ry] = __builtin_amdgcn_mfma_f32_16x16x32_f16(kb_h, F1[ky], acc[ry], 0, 0, 0);
            }
        }
    }

    if (m < 8) {
#pragma unroll
        for (int ry = 0; ry < 4; ry++) {
            int y = by + wy * 4 + ry;
            half4 hv = {(_Float16)acc[ry][0], (_Float16)acc[ry][1],
                        (_Float16)acc[ry][2], (_Float16)acc[ry][3]};
            *(half4*)(f3 + (size_t)m * HW + (size_t)y * W + bx + wx * 16 + b * 4) = hv;
        }
    }
}

// ---------------- stdfuse v7: channel-pair packed f16 (v_pk) phase 2, 4 z-iters ----------------
// raw2 holds h2 {ch_a, ch_b}; phase 2 entirely packed f16 (no conversions); hsqh entry
// = 4x h2 {sA,sB,qA,qB} pairs; phase 3 sums half8. LDS ~46 KB -> 3 blocks/CU.
__global__ __launch_bounds__(256) void stdfuse_fused(const _Float16* __restrict__ f3all,
                                                     const float* __restrict__ fw,
                                                     const float* __restrict__ fb,
                                                     const float* __restrict__ stats,
                                                     float* __restrict__ out) {
    __shared__ __align__(16) h2 raw2[46 * 50];          // 9200 B
    __shared__ __align__(16) _Float16 hsqh[3][46 * 132]; // 36432 B (row stride 264 B)
    __shared__ int rowOff[46];      // reflected gy * W (element offset)
    __shared__ int gxcol[46];       // reflected gx
    int tid = threadIdx.x;
    int xq = tid & 15, yp = tid >> 4;
    int bx = blockIdx.x * 32, by = blockIdx.y * 32;
    int batch = blockIdx.z;
    const _Float16* f3 = f3all + (size_t)batch * 8 * HW;

    if (tid < 46) {
        int gy = by + tid - 7;
        gy = gy < 0 ? -gy : (gy > 1023 ? 2046 - gy : gy);
        rowOff[tid] = gy * W;
        int gx = bx + tid - 7;
        gx = gx < 0 ? -gx : (gx > 1023 ? 2046 - gx : gx);
        gxcol[tid] = gx;
    }
    __syncthreads();

    // per-thread staging task table (channel-invariant): 2116 = 8*256 + 68 tasks
    int goffB[9];   // global byte offset within a channel plane (f16)
    int laddW[9];   // dword index into raw2
    const bool k8 = tid < 68;
#pragma unroll
    for (int k = 0; k < 9; k++) {
        int idx = tid + k * 256;
        int idc = idx < 2116 ? idx : 2115;
        int r = idc / 46, c = idc - r * 46;
        goffB[k] = (rowOff[r] + gxcol[c]) * 2;
        laddW[k] = r * 50 + c;
    }

    float wwin[3] = {fw[0] * 0.125f, fw[1] * 0.125f, fw[2] * 0.125f};
    float part[4] = {0.f, 0.f, 0.f, 0.f};

    // prologue: load channel pair 0 (planes 0,1) as raw u16 bits
    unsigned sa[9], sb[9];
    {
        const char* pa = (const char*)f3;
        const char* pb = (const char*)(f3 + HW);
#pragma unroll
        for (int k = 0; k < 8; k++) {
            sa[k] = *(const unsigned short*)(pa + goffB[k]);
            sb[k] = *(const unsigned short*)(pb + goffB[k]);
        }
        sa[8] = k8 ? *(const unsigned short*)(pa + goffB[8]) : 0u;
        sb[8] = k8 ? *(const unsigned short*)(pb + goffB[8]) : 0u;
    }

    for (int zp = 0; zp < 4; zp++) {
        // write staged pair to raw2 (safe: prior phase-2 raw reads ended at barrier B)
        unsigned* rb = (unsigned*)raw2;
#pragma unroll
        for (int k = 0; k < 8; k++) rb[laddW[k]] = sa[k] | (sb[k] << 16);
        if (k8) rb[laddW[8]] = sa[8] | (sb[8] << 16);

        // T14: issue next pair's loads BEFORE the barrier; latency hides under phase 2+3
        if (zp < 3) {
            const char* na = (const char*)(f3 + (size_t)(2 * zp + 2) * HW);
            const char* nb = (const char*)(f3 + (size_t)(2 * zp + 3) * HW);
#pragma unroll
            for (int k = 0; k < 8; k++) {
                sa[k] = *(const unsigned short*)(na + goffB[k]);
                sb[k] = *(const unsigned short*)(nb + goffB[k]);
            }
            if (k8) {
                sa[8] = *(const unsigned short*)(na + goffB[8]);
                sb[8] = *(const unsigned short*)(nb + goffB[8]);
            }
        }
        __syncthreads();   // A: raw2 ready; prior phase-3 hsqh reads complete

        // phase 2: horizontal window sums, fully packed f16 (both channels per op)
        for (int idx = tid; idx < 736; idx += 256) {
            int r = idx >> 4, xh = idx & 15;
            const h2* rp = raw2 + r * 50 + 2 * xh;
            h2 v[16], w[16];
#pragma unroll
            for (int k = 0; k < 16; k++) v[k] = rp[k];
#pragma unroll
            for (int k = 0; k < 16; k++) w[k] = v[k] * v[k];
            h2 ms = v[6] + v[7] + v[8] + v[9];
            h2 mq = w[6] + w[7] + w[8] + w[9];
            h2 sA5 = v[5] + ms, sB5 = ms + v[10];
            h2 qA5 = w[5] + mq, qB5 = mq + w[10];
            h2 sA9 = sA5 + v[3] + v[4] + v[10] + v[11];
            h2 sB9 = sB5 + v[4] + v[5] + v[11] + v[12];
            h2 qA9 = qA5 + w[3] + w[4] + w[10] + w[11];
            h2 qB9 = qB5 + w[4] + w[5] + w[11] + w[12];
            h2 sA15 = sA9 + v[0] + v[1] + v[2] + v[12] + v[13] + v[14];
            h2 sB15 = sB9 + v[1] + v[2] + v[3] + v[13] + v[14] + v[15];
            h2 qA15 = qA9 + w[0] + w[1] + w[2] + w[12] + w[13] + w[14];
            h2 qB15 = qB9 + w[1] + w[2] + w[3] + w[13] + w[14] + w[15];
            int ho = r * 132 + 8 * xh;
            uint4v u0, u1, u2;
            u0.x = __builtin_bit_cast(unsigned, sA5);
            u0.y = __builtin_bit_cast(unsigned, sB5);
            u0.z = __builtin_bit_cast(unsigned, qA5);
            u0.w = __builtin_bit_cast(unsigned, qB5);
            u1.x = __builtin_bit_cast(unsigned, sA9);
            u1.y = __builtin_bit_cast(unsigned, sB9);
            u1.z = __builtin_bit_cast(unsigned, qA9);
            u1.w = __builtin_bit_cast(unsigned, qB9);
            u2.x = __builtin_bit_cast(unsigned, sA15);
            u2.y = __builtin_bit_cast(unsigned, sB15);
            u2.z = __builtin_bit_cast(unsigned, qA15);
            u2.w = __builtin_bit_cast(unsigned, qB15);
            *(uint4v*)&hsqh[0][ho] = u0;
            *(uint4v*)&hsqh[1][ho] = u1;
            *(uint4v*)&hsqh[2][ho] = u2;
        }
        __syncthreads();   // B: hsqh ready; all raw2 reads complete

        // phase 3: vertical sums in packed f16 (half8, dual accumulators) + f32 finishing
#pragma unroll
        for (int wi = 0; wi < 3; wi++) {
            const int wlen = (wi == 0) ? 5 : ((wi == 1) ? 9 : 15);
            const int r0 = 2 * yp + 7 - (wlen >> 1);
            const float inv = 1.0f / (float)(wlen * wlen);
            const float ww = wwin[wi];
            const _Float16* basep = &hsqh[wi][8 * xq];
            half8 first = *(const half8*)(basep + r0 * 132);
            half8 e = first;
            half8 o = *(const half8*)(basep + (r0 + 1) * 132);
#pragma unroll
            for (int k = 2; k + 1 < wlen; k += 2) {
                e += *(const half8*)(basep + (r0 + k) * 132);
                o += *(const half8*)(basep + (r0 + k + 1) * 132);
            }
            e += *(const half8*)(basep + (r0 + wlen - 1) * 132);   // last even row
            half8 tot = e + o;
            half8 last = *(const half8*)(basep + (r0 + wlen) * 132);
            half8 sh = tot - first + last;
            // layout: [0,1]=sA(a,b) [2,3]=sB(a,b) [4,5]=qA(a,b) [6,7]=qB(a,b)
#pragma unroll
            for (int ch = 0; ch < 2; ch++) {
                float mA0 = (float)tot[0 + ch] * inv, m2A0 = (float)tot[4 + ch] * inv;
                part[0] += ww * fast_sqrtf(fmaxf(m2A0 - mA0 * mA0, 0.f) + 1e-8f);
                float mB0 = (float)tot[2 + ch] * inv, m2B0 = (float)tot[6 + ch] * inv;
                part[1] += ww * fast_sqrtf(fmaxf(m2B0 - mB0 * mB0, 0.f) + 1e-8f);
                float mA1 = (float)sh[0 + ch] * inv, m2A1 = (float)sh[4 + ch] * inv;
                part[2] += ww * fast_sqrtf(fmaxf(m2A1 - mA1 * mA1, 0.f) + 1e-8f);
                float mB1 = (float)sh[2 + ch] * inv, m2B1 = (float)sh[6 + ch] * inv;
                part[3] += ww * fast_sqrtf(fmaxf(m2B1 - mB1 * mB1, 0.f) + 1e-8f);
            }
        }
        // no barrier: next iter writes raw2 (disjoint from hsqh); hsqh rewritten only after next barrier A
    }

    // epilogue: fused value -> per-channel threshold + sigmoid, direct output write
    float fb0 = fb[0];
    int gy = by + 2 * yp, gx = bx + 2 * xq;
#pragma unroll
    for (int c = 0; c < 4; c++) {
        float lo = stats[(batch * 4 + c) * 2];
        float up = stats[(batch * 4 + c) * 2 + 1];
        float inv = 1.f / (up - lo);
        float v[4];
#pragma unroll
        for (int p = 0; p < 4; p++) {
            float ns = (part[p] + fb0 - lo) * inv;
            ns = fminf(fmaxf(ns, 0.f), 1.f);
            v[p] = 1.f / (1.f + fast_expf(3.f - 6.f * ns));
        }
        float* plane = out + ((size_t)(batch * 4 + c)) * HW;
        *(float2*)(plane + (size_t)gy * W + gx) = make_float2(v[0], v[1]);
        *(float2*)(plane + (size_t)(gy + 1) * W + gx) = make_float2(v[2], v[3]);
    }
}

extern "C" void kernel_launch(void* const* d_in, const int* in_sizes, int n_in,
                              void* d_out, int out_size, void* d_ws, size_t ws_size,
                              hipStream_t stream) {
    (void)in_sizes; (void)n_in; (void)out_size;
    const float* x = (const float*)d_in[0];
    const float* w1 = (const float*)d_in[1];
    const float* b1 = (const float*)d_in[2];
    const float* w2 = (const float*)d_in[3];
    const float* b2 = (const float*)d_in[4];
    const float* w3 = (const float*)d_in[5];
    const float* b3 = (const float*)d_in[6];
    const float* chw = (const float*)d_in[7];
    const float* fw = (const float*)d_in[8];
    const float* fb = (const float*)d_in[9];
    float* out = (float*)d_out;

    char* ws = (char*)d_ws;
    float* stats = (float*)ws;                         // 32 f
    double* part = (double*)(ws + 256);                // 1024 d, ends 8448
    _Float16* w1a = (_Float16*)(ws + 8448);            // 2048 f16, ends 12544
    _Float16* w3f = (_Float16*)(ws + 24832);           // 3072 f16, ends 30976
    _Float16* w2bh = (_Float16*)(ws + 37120);          // 4608 f16, ends 46336
    _Float16* f3all = (_Float16*)(ws + 65536);         // 4 batches x 8 ch x HW f16 = 64 MB
    _Float16* f2n = (_Float16*)(ws + 67174400);        // h-only planes of 32 MB

    // wide mode: 4 f2n planes -> single conv12 + single conv3 dispatch (needs 192.05 MB ws)
    const size_t PLANE = (size_t)16 * HW;              // f16 elements per f2n plane
    const size_t WIDE_WS = 67174400ULL + 4ULL * PLANE * sizeof(_Float16);
    bool wide = ws_size >= WIDE_WS;

    stats_partial<<<512, 256, 0, stream>>>(x, part);
    stats_final_prep<<<1, 256, 0, stream>>>(part, chw, w1, w2, w3, stats, w1a, w3f, w2bh);

    if (wide) {
        conv12_mfma<<<dim3(32, 128, 4), 256, 0, stream>>>(x, w1a, b1, w2bh, b2, f2n, PLANE, 0);
        conv3_mfma<<<dim3(32, 128, 4), 256, 0, stream>>>(f2n, PLANE, 0, w3f, b3, f3all);
    } else {
        for (int b = 0; b < 4; b++) {
            conv12_mfma<<<dim3(32, 128, 1), 256, 0, stream>>>(x, w1a, b1, w2bh, b2, f2n, 0, b);
            conv3_mfma<<<dim3(32, 128, 1), 256, 0, stream>>>(f2n, 0, b, w3f, b3, f3all);
        }
    }
    stdfuse_fused<<<dim3(32, 32, 4), 256, 0, stream>>>(f3all, fw, fb, stats, out);
}

// Round 13
// 312.132 us; speedup vs baseline: 1.2563x; 1.2563x over previous
//
#include <hip/hip_runtime.h>
#include <math.h>

#define H 1024
#define W 1024
#define HW (H * W)

typedef _Float16 half8 __attribute__((ext_vector_type(8)));
typedef _Float16 half4 __attribute__((ext_vector_type(4)));
typedef _Float16 h2 __attribute__((ext_vector_type(2)));
typedef float f32x4 __attribute__((ext_vector_type(4)));
typedef unsigned uint4v __attribute__((ext_vector_type(4)));
typedef unsigned uint2v __attribute__((ext_vector_type(2)));

__device__ __forceinline__ float fast_sqrtf(float x) { return __builtin_amdgcn_sqrtf(x); }
__device__ __forceinline__ float fast_expf(float x) { return __builtin_amdgcn_exp2f(x * 1.44269504088896340736f); }

__device__ __forceinline__ h2 pkrtz(float a, float b) {
    return __builtin_bit_cast(h2, __builtin_amdgcn_cvt_pkrtz(a, b));
}

// ---------------- stats pass 1: partial sum/sumsq per (b,c) chunk ----------------
__global__ __launch_bounds__(256) void stats_partial(const float* __restrict__ x,
                                                     double* __restrict__ part) {
    int blk = blockIdx.x;
    int bc = blk >> 5;
    int j = blk & 31;
    const float* p = x + (size_t)bc * HW + (size_t)j * (HW / 32);
    int tid = threadIdx.x;
    double s = 0.0, q = 0.0;
    const float4* p4 = (const float4*)p;
    for (int i = tid; i < (HW / 32) / 4; i += 256) {
        float4 v = p4[i];
        s += (double)v.x + (double)v.y + (double)v.z + (double)v.w;
        q += (double)v.x * v.x + (double)v.y * v.y + (double)v.z * v.z + (double)v.w * v.w;
    }
    __shared__ double ls[256], lq[256];
    ls[tid] = s;
    lq[tid] = q;
    __syncthreads();
    for (int ofs = 128; ofs > 0; ofs >>= 1) {
        if (tid < ofs) { ls[tid] += ls[tid + ofs]; lq[tid] += lq[tid + ofs]; }
        __syncthreads();
    }
    if (tid == 0) {
        part[blk * 2] = ls[0];
        part[blk * 2 + 1] = lq[0];
    }
}

// ---------------- stats pass 2 + weight prep (h-only conv weights) ----------------
__global__ __launch_bounds__(256) void stats_final_prep(const double* __restrict__ part,
                                                        const float* __restrict__ chw,
                                                        const float* __restrict__ w1,
                                                        const float* __restrict__ w2,
                                                        const float* __restrict__ w3,
                                                        float* __restrict__ stats,
                                                        _Float16* __restrict__ w1a,
                                                        _Float16* __restrict__ w3f,
                                                        _Float16* __restrict__ w2bh) {
    int tid = threadIdx.x;
    __shared__ float cw[4];
    if (tid == 0) {
        float m = fmaxf(fmaxf(chw[0], chw[1]), fmaxf(chw[2], chw[3]));
        float e0 = expf(chw[0] - m), e1 = expf(chw[1] - m);
        float e2 = expf(chw[2] - m), e3 = expf(chw[3] - m);
        float s = e0 + e1 + e2 + e3;
        cw[0] = e0 / s; cw[1] = e1 / s; cw[2] = e2 / s; cw[3] = e3 / s;
    }
    __syncthreads();
    if (tid < 16) {
        double s = 0.0, q = 0.0;
        for (int j = 0; j < 32; j++) {
            s += part[(tid * 32 + j) * 2];
            q += part[(tid * 32 + j) * 2 + 1];
        }
        double n = (double)HW;
        double var = (q - s * s / n) / (n - 1.0);
        if (var < 0) var = 0;
        float gs = (float)sqrt(var);
        int c = tid & 3;
        float gf = fminf(fmaxf(gs * 5.0f, 0.5f), 2.0f);
        float cf = fminf(fmaxf(gs * cw[c] * 2.0f, 0.8f), 1.2f);
        stats[tid * 2] = 0.05f * gf * cf;
        stats[tid * 2 + 1] = 0.20f * gf * cf;
    }
    // conv1 A-frags, h-only: 4 sets (c,h) of 64 lanes x 8
    for (int i = tid; i < 256; i += 256) {
        int s = i >> 6, l = i & 63;
        int c = s >> 1, h = s & 1;
        int m = l & 15, cg = l >> 4;
        int co = h * 16 + m;
#pragma unroll
        for (int j = 0; j < 8; j++) {
            int k = c * 32 + cg * 8 + j;
            float v = 0.f;
            if (k < 36) {
                int t = k >> 2, ci = k & 3;
                v = w1[(co * 4 + ci) * 9 + t];
            }
            w1a[i * 8 + j] = (_Float16)v;
        }
    }
    for (int idx = tid; idx < 576; idx += 256) {           // conv2 B-frags (h only)
        int t = idx >> 6, l = idx & 63;
        int co = l & 15, cg = l >> 4;
#pragma unroll
        for (int j = 0; j < 8; j++) {
            int ci = cg * 8 + j;
            w2bh[idx * 8 + j] = (_Float16)w2[(co * 32 + ci) * 9 + t];
        }
    }
    for (int idx = tid; idx < 384; idx += 256) {           // conv3 B-frags: 6 sets (ky,grp) h-only
        int t = idx >> 6, l = idx & 63;
        int ky = t / 2, grp = t & 1;
        int co = l & 15, bq = l >> 4;
#pragma unroll
        for (int j = 0; j < 8; j++) {
            int k = bq * 8 + j;
            float v = 0.f;
            if (co < 8) {
                if (grp == 0) {
                    int kxp = k >> 4, ci = k & 15;
                    v = w3[((co * 16 + ci) * 3 + ky) * 3 + kxp];
                } else if (k < 16) {
                    v = w3[((co * 16 + k) * 3 + ky) * 3 + 2];
                }
            }
            w3f[idx * 8 + j] = (_Float16)v;
        }
    }
}

// ---------------- fused conv1+conv2, f16 h-only MFMA ----------------
// v11 (proven): x halo staged as channel-pair-packed f16; A-operand from ds_read_b32.
__global__ __launch_bounds__(256, 5) void conv12_mfma(const float* __restrict__ x,
                                                      const _Float16* __restrict__ w1a,
                                                      const float* __restrict__ b1,
                                                      const _Float16* __restrict__ wbh,
                                                      const float* __restrict__ b2,
                                                      _Float16* __restrict__ f2n,
                                                      size_t f2n_bstride, int batch0) {
    __shared__ __align__(16) char smem[30656];
    char* f1t = smem;                                  // 10*34*80 = 27200 B (h-only)
    unsigned* xp = (unsigned*)(smem + 27200);          // 2 planes x [12][36] u32 packed f16 pairs
    int tid = threadIdx.x;
    int lane = tid & 63;
    int wid = tid >> 6;
    int bx = blockIdx.x * 32, by = blockIdx.y * 8;
    int n = lane & 15, cg = lane >> 4;
    int m = lane & 15, b = lane >> 4;
    const float* xb = x + (size_t)(batch0 + blockIdx.z) * 4 * HW;
    _Float16* f2nb = f2n + (size_t)blockIdx.z * f2n_bstride;

    // phase 1: stage x halo (rows by-2..by+9, cols bx-2..bx+33) as packed f16 channel pairs
    {
        int idx = tid;
        int r = tid / 36, c = tid - r * 36, plane = 0;
#pragma unroll
        for (int it = 0; it < 4; ++it) {
            if (idx < 864) {
                int gy = by + r - 2, gx = bx + c - 2;
                float v0 = 0.f, v1 = 0.f;
                if ((unsigned)gy < H && (unsigned)gx < W) {
                    const float* pp = xb + (size_t)(2 * plane) * HW + gy * W + gx;
                    v0 = pp[0];
                    v1 = pp[HW];
                }
                xp[idx] = __builtin_bit_cast(unsigned, pkrtz(v0, v1));
            }
            idx += 256;
            c += 4; if (c >= 36) { c -= 36; r += 1; }
            r += 7; if (r >= 12) { r -= 12; plane += 1; }
        }
    }

    half8 Wf00 = *(const half8*)(w1a + (0 * 64 + lane) * 8);
    half8 Wf01 = *(const half8*)(w1a + (1 * 64 + lane) * 8);
    half8 Wf10 = *(const half8*)(w1a + (2 * 64 + lane) * 8);
    half8 Wf11 = *(const half8*)(w1a + (3 * 64 + lane) * 8);
    float bias1[8];
#pragma unroll
    for (int h = 0; h < 2; h++)
#pragma unroll
        for (int j = 0; j < 4; j++)
            bias1[h * 4 + j] = b1[h * 16 + cg * 4 + j];
    half8 Bh[9];
#pragma unroll
    for (int t = 0; t < 9; t++)
        Bh[t] = *(const half8*)(wbh + (t * 64 + lane) * 8);
    f32x4 binit;
#pragma unroll
    for (int j = 0; j < 4; j++) binit[j] = b2[b * 4 + j];

    int t0 = 2 * cg, t1 = 2 * cg + 1;
    int dy0 = (t0 * 11) >> 5, dx0 = t0 - 3 * dy0;
    int dy1 = (t1 * 11) >> 5, dx1 = t1 - 3 * dy1;
    int off0 = dy0 * 36 + dx0, off1 = dy1 * 36 + dx1;
    __syncthreads();

    // phase 2: conv1 via MFMA; 22 tiles of 16 px cover the 340-px halo
#pragma unroll 1
    for (int tt = wid; tt < 22; tt += 4) {
        int p = tt * 16 + n;
        bool valid = p < 340;
        int pc = valid ? p : 339;
        int ry = pc / 34, cx = pc - ry * 34;
        int gy = by + ry - 1, gx = bx + cx - 1;
        bool ok = ((unsigned)gy < H) && ((unsigned)gx < W);
        int base = ry * 36 + cx;
        uint4v uv;
        uv.x = xp[base + off0];
        uv.y = xp[432 + base + off0];
        uv.z = xp[base + off1];
        uv.w = xp[432 + base + off1];
        half8 Xh0 = __builtin_bit_cast(half8, uv);
        half8 Xh1 = {0, 0, 0, 0, 0, 0, 0, 0};
        if (cg == 0) {
            uint4v uw = {0, 0, 0, 0};
            uw.x = xp[base + 74];                      // tap 8 (dy=2,dx=2), ch0|ch1
            uw.y = xp[432 + base + 74];                // ch2|ch3
            Xh1 = __builtin_bit_cast(half8, uw);
        }
        f32x4 d0, d1;
#pragma unroll
        for (int j = 0; j < 4; j++) { d0[j] = bias1[j]; d1[j] = bias1[4 + j]; }
        d0 = __builtin_amdgcn_mfma_f32_16x16x32_f16(Wf00, Xh0, d0, 0, 0, 0);
        d0 = __builtin_amdgcn_mfma_f32_16x16x32_f16(Wf10, Xh1, d0, 0, 0, 0);
        d1 = __builtin_amdgcn_mfma_f32_16x16x32_f16(Wf01, Xh0, d1, 0, 0, 0);
        d1 = __builtin_amdgcn_mfma_f32_16x16x32_f16(Wf11, Xh1, d1, 0, 0, 0);
        if (valid) {
            char* pxb = f1t + ry * 2720 + cx * 80;
#pragma unroll
            for (int h = 0; h < 2; h++) {
                f32x4 d = h ? d1 : d0;
                half4 hq;
#pragma unroll
                for (int j = 0; j < 4; j++) {
                    float v = d[j];
                    v = fmaxf(v, 0.2f * v);
                    v = ok ? v : 0.f;
                    hq[j] = (_Float16)v;
                }
                *(half4*)(pxb + (h * 4 + cg) * 8) = hq;
            }
        }
    }
    __syncthreads();

    // phase 3: conv2 via rolling-row f16 MFMA, D = W*X (lane owns px, 4 co)
    int wx = wid & 1, wy = wid >> 1;
    f32x4 acc2[4];
#pragma unroll
    for (int r = 0; r < 4; r++) acc2[r] = binit;
#pragma unroll
    for (int iy = 0; iy < 6; iy++) {
        int f1row = wy * 4 + iy;
        half8 ah[3];
#pragma unroll
        for (int kx = 0; kx < 3; kx++) {
            int pxi = wx * 16 + m + kx;
            ah[kx] = *(const half8*)(f1t + f1row * 2720 + pxi * 80 + b * 16);
        }
#pragma unroll
        for (int kx = 0; kx < 3; kx++) {
#pragma unroll
            for (int ry = 0; ry < 4; ry++) {
                if (ry >= iy - 2 && ry <= iy) {
                    const int t = (iy - ry) * 3 + kx;
                    acc2[ry] = __builtin_amdgcn_mfma_f32_16x16x32_f16(Bh[t], ah[kx], acc2[ry], 0, 0, 0);
                }
            }
        }
    }

    // epilogue (h-only f2n): leaky -> f16 -> direct store, 32B/px
    int x0 = bx + wx * 16 + m;
    int y0 = by + wy * 4;
    int co_off = b * 4;
#pragma unroll
    for (int ry = 0; ry < 4; ry++) {
        half4 hq;
#pragma unroll
        for (int j = 0; j < 4; j++) {
            float v = acc2[ry][j];
            v = fmaxf(v, 0.2f * v);
            hq[j] = (_Float16)v;
        }
        *(half4*)(f2nb + ((size_t)(y0 + ry) * W + x0) * 16 + co_off) = hq;
    }
}

// ---------------- conv3: h-only f16 MFMA, 32x8 tile, f16 output ----------------
__global__ __launch_bounds__(256) void conv3_mfma(const _Float16* __restrict__ f2n,
                                                  size_t f2n_bstride, int batch0,
                                                  const _Float16* __restrict__ w3f,
                                                  const float* __restrict__ bias,
                                                  _Float16* __restrict__ f3all) {
    __shared__ __align__(16) char st[10 * 34 * 40];    // 13600 B
    int tid = threadIdx.x;
    int lane = tid & 63;
    int wid = tid >> 6;
    int bx = blockIdx.x * 32, by = blockIdx.y * 8;
    const _Float16* f2nb = f2n + (size_t)blockIdx.z * f2n_bstride;
    _Float16* f3 = f3all + (size_t)(batch0 + blockIdx.z) * 8 * HW;

    // stage: rows by-1..by+8, px bx-1..bx+32, 2 x 16B chunks per px (680 tasks)
    for (int idx = tid; idx < 680; idx += 256) {
        int c0 = idx & 1;
        int rp = idx >> 1;
        int r = rp / 34, p = rp - r * 34;
        int gy = by + r - 1, gx = bx + p - 1;
        half8 v = {0, 0, 0, 0, 0, 0, 0, 0};
        if ((unsigned)gy < H && (unsigned)gx < W)
            v = *(const half8*)(f2nb + ((size_t)gy * W + gx) * 16 + c0 * 8);
        *(half8*)(st + r * 1360 + p * 40 + c0 * 16) = v;
    }

    half8 F0[3], F1[3];                                // per ky: grp0-h, grp1-h
#pragma unroll
    for (int ky = 0; ky < 3; ky++) {
        F0[ky] = *(const half8*)(w3f + ((ky * 2 + 0) * 64 + lane) * 8);
        F1[ky] = *(const half8*)(w3f + ((ky * 2 + 1) * 64 + lane) * 8);
    }
    int m = lane & 15, b = lane >> 4;
    int halfco = b & 1, kxp = b >> 1;
    int wx = wid & 1, wy = wid >> 1;
    float bc = (m < 8) ? bias[m] : 0.f;
    f32x4 acc[4];
#pragma unroll
    for (int r = 0; r < 4; r++) acc[r] = (f32x4){bc, bc, bc, bc};
    int pA = wx * 16 + m + kxp;                        // halo-local px for A (kx -1,0)
    int pB = wx * 16 + m + 2;                          // halo-local px for B (kx +1)
    __syncthreads();

#pragma unroll
    for (int iy = 0; iy < 6; iy++) {
        const char* rp = st + (wy * 4 + iy) * 1360;
        half8 ka_h = *(const half8*)(rp + pA * 40 + halfco * 16);
        half8 kb_h = *(const half8*)(rp + pB * 40 + halfco * 16);
#pragma unroll
        for (int ry = 0; ry < 4; ry++) {
            if (ry >= iy - 2 && ry <= iy) {
                const int ky = iy - ry;
                acc[ry] = __builtin_amdgcn_mfma_f32_16x16x32_f16(ka_h, F0[ky], acc[ry], 0, 0, 0);
                acc[ry] = __builtin_amdgcn_mfma_f32_16x16x32_f16(kb_h, F1[ky], acc[ry], 0, 0, 0);
            }
        }
    }

    if (m < 8) {
#pragma unroll
        for (int ry = 0; ry < 4; ry++) {
            int y = by + wy * 4 + ry;
            half4 hv = {(_Float16)acc[ry][0], (_Float16)acc[ry][1],
                        (_Float16)acc[ry][2], (_Float16)acc[ry][3]};
            *(half4*)(f3 + (size_t)m * HW + (size_t)y * W + bx + wx * 16 + b * 4) = hv;
        }
    }
}

// ---------------- stdfuse v8: v6 layout + A/B-pair packed-f16 phase 2 ----------------
// Same LDS (24 KB, 6 blocks/CU) and phase 3 as the proven v6; phase 2 packs the two
// pixels each thread owns into h2 lanes: vp[k] = {v[k], v[k+1]} built from 8 aligned
// ds_read_b32 + 7 v_alignbit. All sums in v_pk_*_f16, zero conversions.
__global__ __launch_bounds__(256) void stdfuse_fused(const _Float16* __restrict__ f3all,
                                                     const float* __restrict__ fw,
                                                     const float* __restrict__ fb,
                                                     const float* __restrict__ stats,
                                                     float* __restrict__ out) {
    __shared__ __align__(16) _Float16 raw[46 * 50];
    __shared__ __align__(16) _Float16 hsqh[3][46 * 68];
    __shared__ int rowOff[46];      // reflected gy * W (element offset)
    __shared__ int gxcol[46];       // reflected gx
    int tid = threadIdx.x;
    int xq = tid & 15, yp = tid >> 4;
    int bx = blockIdx.x * 32, by = blockIdx.y * 32;
    int batch = blockIdx.z;
    const _Float16* f3 = f3all + (size_t)batch * 8 * HW;

    if (tid < 46) {
        int gy = by + tid - 7;
        gy = gy < 0 ? -gy : (gy > 1023 ? 2046 - gy : gy);
        rowOff[tid] = gy * W;
        int gx = bx + tid - 7;
        gx = gx < 0 ? -gx : (gx > 1023 ? 2046 - gx : gx);
        gxcol[tid] = gx;
    }
    __syncthreads();

    // per-thread staging task table (channel-invariant): 2116 = 8*256 + 68 tasks
    int goffB[9];   // global byte offset within a channel plane (f16)
    int laddB[9];   // LDS byte offset into raw (f16)
    const bool k8 = tid < 68;
#pragma unroll
    for (int k = 0; k < 9; k++) {
        int idx = tid + k * 256;
        int idc = idx < 2116 ? idx : 2115;
        int r = idc / 46, c = idc - r * 46;
        goffB[k] = (rowOff[r] + gxcol[c]) * 2;
        laddB[k] = (r * 50 + c) * 2;
    }

    float wwin[3] = {fw[0] * 0.125f, fw[1] * 0.125f, fw[2] * 0.125f};
    float part[4] = {0.f, 0.f, 0.f, 0.f};

    // prologue: load channel 0 into registers (raw f16 bits, no conversion)
    unsigned short stg[9];
    {
        const char* src = (const char*)f3;
#pragma unroll
        for (int k = 0; k < 8; k++) stg[k] = *(const unsigned short*)(src + goffB[k]);
        stg[8] = k8 ? *(const unsigned short*)(src + goffB[8]) : (unsigned short)0;
    }

    for (int z = 0; z < 8; z++) {
        // write staged registers to raw (safe: prior phase-2 raw reads ended at barrier B)
        char* rb = (char*)raw;
#pragma unroll
        for (int k = 0; k < 8; k++) *(unsigned short*)(rb + laddB[k]) = stg[k];
        if (k8) *(unsigned short*)(rb + laddB[8]) = stg[8];

        // T14: issue next channel's loads BEFORE the barrier; latency hides under phase 2+3
        if (z < 7) {
            const char* nsrc = (const char*)(f3 + (size_t)(z + 1) * HW);
#pragma unroll
            for (int k = 0; k < 8; k++) stg[k] = *(const unsigned short*)(nsrc + goffB[k]);
            if (k8) stg[8] = *(const unsigned short*)(nsrc + goffB[8]);
        }
        __syncthreads();   // A: raw ready; prior phase-3 hsqh reads complete

        // phase 2: A/B-pair packed horizontal window sums -> half4 {sA,sB,qA,qB}
        for (int idx = tid; idx < 736; idx += 256) {
            int r = idx >> 4, xh = idx & 15;
            const unsigned* rp = (const unsigned*)raw + r * 25 + xh;
            unsigned d[8];
#pragma unroll
            for (int i = 0; i < 8; i++) d[i] = rp[i];
            h2 vp[15];
#pragma unroll
            for (int i = 0; i < 8; i++)
                if (2 * i < 15) vp[2 * i] = __builtin_bit_cast(h2, d[i]);
#pragma unroll
            for (int i = 0; i < 7; i++)
                vp[2 * i + 1] = __builtin_bit_cast(h2, __builtin_amdgcn_alignbit(d[i + 1], d[i], 16));
            h2 wp[15];
#pragma unroll
            for (int k = 0; k < 15; k++) wp[k] = vp[k] * vp[k];
            h2 s5 = vp[5] + vp[6] + vp[7] + vp[8] + vp[9];
            h2 q5 = wp[5] + wp[6] + wp[7] + wp[8] + wp[9];
            h2 s9 = s5 + vp[3] + vp[4] + vp[10] + vp[11];
            h2 q9 = q5 + wp[3] + wp[4] + wp[10] + wp[11];
            h2 s15 = s9 + vp[0] + vp[1] + vp[2] + vp[12] + vp[13] + vp[14];
            h2 q15 = q9 + wp[0] + wp[1] + wp[2] + wp[12] + wp[13] + wp[14];
            int ho = r * 68 + 4 * xh;
            uint2v u0, u1, u2;
            u0.x = __builtin_bit_cast(unsigned, s5);
            u0.y = __builtin_bit_cast(unsigned, q5);
            u1.x = __builtin_bit_cast(unsigned, s9);
            u1.y = __builtin_bit_cast(unsigned, q9);
            u2.x = __builtin_bit_cast(unsigned, s15);
            u2.y = __builtin_bit_cast(unsigned, q15);
            *(uint2v*)&hsqh[0][ho] = u0;
            *(uint2v*)&hsqh[1][ho] = u1;
            *(uint2v*)&hsqh[2][ho] = u2;
        }
        __syncthreads();   // B: hsqh ready; all raw reads complete

        // phase 3: vertical sums in packed f16 (dual accumulators) + f32 finishing
#pragma unroll
        for (int wi = 0; wi < 3; wi++) {
            const int wlen = (wi == 0) ? 5 : ((wi == 1) ? 9 : 15);
            const int r0 = 2 * yp + 7 - (wlen >> 1);
            const float inv = 1.0f / (float)(wlen * wlen);
            const float ww = wwin[wi];
            const _Float16* basep = &hsqh[wi][4 * xq];
            half4 first = *(const half4*)(basep + r0 * 68);
            half4 e = first;
            half4 o = *(const half4*)(basep + (r0 + 1) * 68);
#pragma unroll
            for (int k = 2; k + 1 < wlen; k += 2) {
                e += *(const half4*)(basep + (r0 + k) * 68);
                o += *(const half4*)(basep + (r0 + k + 1) * 68);
            }
            e += *(const half4*)(basep + (r0 + wlen - 1) * 68);   // last even row
            half4 tot = e + o;
            half4 last = *(const half4*)(basep + (r0 + wlen) * 68);
            half4 sh = tot - first + last;
            // layout: [0]=sA [1]=sB [2]=qA [3]=qB
            float sA0 = (float)tot[0], sB0 = (float)tot[1];
            float qA0 = (float)tot[2], qB0 = (float)tot[3];
            float sA1 = (float)sh[0],  sB1 = (float)sh[1];
            float qA1 = (float)sh[2],  qB1 = (float)sh[3];
            float mA0 = sA0 * inv, m2A0 = qA0 * inv;
            part[0] += ww * fast_sqrtf(fmaxf(m2A0 - mA0 * mA0, 0.f) + 1e-8f);
            float mB0 = sB0 * inv, m2B0 = qB0 * inv;
            part[1] += ww * fast_sqrtf(fmaxf(m2B0 - mB0 * mB0, 0.f) + 1e-8f);
            float mA1 = sA1 * inv, m2A1 = qA1 * inv;
            part[2] += ww * fast_sqrtf(fmaxf(m2A1 - mA1 * mA1, 0.f) + 1e-8f);
            float mB1 = sB1 * inv, m2B1 = qB1 * inv;
            part[3] += ww * fast_sqrtf(fmaxf(m2B1 - mB1 * mB1, 0.f) + 1e-8f);
        }
        // no barrier: next iter writes raw (disjoint from hsqh); hsqh rewritten only after next barrier A
    }

    // epilogue: fused value -> per-channel threshold + sigmoid, direct output write
    float fb0 = fb[0];
    int gy = by + 2 * yp, gx = bx + 2 * xq;
#pragma unroll
    for (int c = 0; c < 4; c++) {
        float lo = stats[(batch * 4 + c) * 2];
        float up = stats[(batch * 4 + c) * 2 + 1];
        float inv = 1.f / (up - lo);
        float v[4];
#pragma unroll
        for (int p = 0; p < 4; p++) {
            float ns = (part[p] + fb0 - lo) * inv;
            ns = fminf(fmaxf(ns, 0.f), 1.f);
            v[p] = 1.f / (1.f + fast_expf(3.f - 6.f * ns));
        }
        float* plane = out + ((size_t)(batch * 4 + c)) * HW;
        *(float2*)(plane + (size_t)gy * W + gx) = make_float2(v[0], v[1]);
        *(float2*)(plane + (size_t)(gy + 1) * W + gx) = make_float2(v[2], v[3]);
    }
}

extern "C" void kernel_launch(void* const* d_in, const int* in_sizes, int n_in,
                              void* d_out, int out_size, void* d_ws, size_t ws_size,
                              hipStream_t stream) {
    (void)in_sizes; (void)n_in; (void)out_size;
    const float* x = (const float*)d_in[0];
    const float* w1 = (const float*)d_in[1];
    const float* b1 = (const float*)d_in[2];
    const float* w2 = (const float*)d_in[3];
    const float* b2 = (const float*)d_in[4];
    const float* w3 = (const float*)d_in[5];
    const float* b3 = (const float*)d_in[6];
    const float* chw = (const float*)d_in[7];
    const float* fw = (const float*)d_in[8];
    const float* fb = (const float*)d_in[9];
    float* out = (float*)d_out;

    char* ws = (char*)d_ws;
    float* stats = (float*)ws;                         // 32 f
    double* part = (double*)(ws + 256);                // 1024 d, ends 8448
    _Float16* w1a = (_Float16*)(ws + 8448);            // 2048 f16, ends 12544
    _Float16* w3f = (_Float16*)(ws + 24832);           // 3072 f16, ends 30976
    _Float16* w2bh = (_Float16*)(ws + 37120);          // 4608 f16, ends 46336
    _Float16* f3all = (_Float16*)(ws + 65536);         // 4 batches x 8 ch x HW f16 = 64 MB
    _Float16* f2n = (_Float16*)(ws + 67174400);        // h-only planes of 32 MB

    // wide mode: 4 f2n planes -> single conv12 + single conv3 dispatch (needs 192.05 MB ws)
    const size_t PLANE = (size_t)16 * HW;              // f16 elements per f2n plane
    const size_t WIDE_WS = 67174400ULL + 4ULL * PLANE * sizeof(_Float16);
    bool wide = ws_size >= WIDE_WS;

    stats_partial<<<512, 256, 0, stream>>>(x, part);
    stats_final_prep<<<1, 256, 0, stream>>>(part, chw, w1, w2, w3, stats, w1a, w3f, w2bh);

    if (wide) {
        conv12_mfma<<<dim3(32, 128, 4), 256, 0, stream>>>(x, w1a, b1, w2bh, b2, f2n, PLANE, 0);
        conv3_mfma<<<dim3(32, 128, 4), 256, 0, stream>>>(f2n, PLANE, 0, w3f, b3, f3all);
    } else {
        for (int b = 0; b < 4; b++) {
            conv12_mfma<<<dim3(32, 128, 1), 256, 0, stream>>>(x, w1a, b1, w2bh, b2, f2n, 0, b);
            conv3_mfma<<<dim3(32, 128, 1), 256, 0, stream>>>(f2n, 0, b, w3f, b3, f3all);
        }
    }
    stdfuse_fused<<<dim3(32, 32, 4), 256, 0, stream>>>(f3all, fw, fb, stats, out);
}

// Round 14
// 297.467 us; speedup vs baseline: 1.3182x; 1.0493x over previous
//
#include <hip/hip_runtime.h>
#include <math.h>

#define H 1024
#define W 1024
#define HW (H * W)

typedef _Float16 half8 __attribute__((ext_vector_type(8)));
typedef _Float16 half4 __attribute__((ext_vector_type(4)));
typedef _Float16 h2 __attribute__((ext_vector_type(2)));
typedef float f32x4 __attribute__((ext_vector_type(4)));
typedef unsigned uint4v __attribute__((ext_vector_type(4)));
typedef unsigned uint2v __attribute__((ext_vector_type(2)));

__device__ __forceinline__ float fast_sqrtf(float x) { return __builtin_amdgcn_sqrtf(x); }
__device__ __forceinline__ float fast_expf(float x) { return __builtin_amdgcn_exp2f(x * 1.44269504088896340736f); }

__device__ __forceinline__ h2 pkrtz(float a, float b) {
    return __builtin_bit_cast(h2, __builtin_amdgcn_cvt_pkrtz(a, b));
}
__device__ __forceinline__ h2 pk_max(h2 a, h2 b) {
    h2 r;
    asm("v_pk_max_f16 %0, %1, %2" : "=v"(r) : "v"(a), "v"(b));
    return r;
}
__device__ __forceinline__ h2 pk_leaky(h2 v) {
    h2 t = v * (h2){(_Float16)0.2f, (_Float16)0.2f};
    return pk_max(v, t);
}

// ---------------- stats pass 1: partial sum/sumsq per (b,c) chunk ----------------
__global__ __launch_bounds__(256) void stats_partial(const float* __restrict__ x,
                                                     double* __restrict__ part) {
    int blk = blockIdx.x;
    int bc = blk >> 5;
    int j = blk & 31;
    const float* p = x + (size_t)bc * HW + (size_t)j * (HW / 32);
    int tid = threadIdx.x;
    double s = 0.0, q = 0.0;
    const float4* p4 = (const float4*)p;
    for (int i = tid; i < (HW / 32) / 4; i += 256) {
        float4 v = p4[i];
        s += (double)v.x + (double)v.y + (double)v.z + (double)v.w;
        q += (double)v.x * v.x + (double)v.y * v.y + (double)v.z * v.z + (double)v.w * v.w;
    }
    __shared__ double ls[256], lq[256];
    ls[tid] = s;
    lq[tid] = q;
    __syncthreads();
    for (int ofs = 128; ofs > 0; ofs >>= 1) {
        if (tid < ofs) { ls[tid] += ls[tid + ofs]; lq[tid] += lq[tid + ofs]; }
        __syncthreads();
    }
    if (tid == 0) {
        part[blk * 2] = ls[0];
        part[blk * 2 + 1] = lq[0];
    }
}

// ---------------- stats pass 2 + weight prep (h-only conv weights) ----------------
__global__ __launch_bounds__(256) void stats_final_prep(const double* __restrict__ part,
                                                        const float* __restrict__ chw,
                                                        const float* __restrict__ w1,
                                                        const float* __restrict__ w2,
                                                        const float* __restrict__ w3,
                                                        float* __restrict__ stats,
                                                        _Float16* __restrict__ w1a,
                                                        _Float16* __restrict__ w3f,
                                                        _Float16* __restrict__ w2bh) {
    int tid = threadIdx.x;
    __shared__ float cw[4];
    if (tid == 0) {
        float m = fmaxf(fmaxf(chw[0], chw[1]), fmaxf(chw[2], chw[3]));
        float e0 = expf(chw[0] - m), e1 = expf(chw[1] - m);
        float e2 = expf(chw[2] - m), e3 = expf(chw[3] - m);
        float s = e0 + e1 + e2 + e3;
        cw[0] = e0 / s; cw[1] = e1 / s; cw[2] = e2 / s; cw[3] = e3 / s;
    }
    __syncthreads();
    if (tid < 16) {
        double s = 0.0, q = 0.0;
        for (int j = 0; j < 32; j++) {
            s += part[(tid * 32 + j) * 2];
            q += part[(tid * 32 + j) * 2 + 1];
        }
        double n = (double)HW;
        double var = (q - s * s / n) / (n - 1.0);
        if (var < 0) var = 0;
        float gs = (float)sqrt(var);
        int c = tid & 3;
        float gf = fminf(fmaxf(gs * 5.0f, 0.5f), 2.0f);
        float cf = fminf(fmaxf(gs * cw[c] * 2.0f, 0.8f), 1.2f);
        stats[tid * 2] = 0.05f * gf * cf;
        stats[tid * 2 + 1] = 0.20f * gf * cf;
    }
    // conv1 A-frags, h-only: 4 sets (c,h) of 64 lanes x 8
    for (int i = tid; i < 256; i += 256) {
        int s = i >> 6, l = i & 63;
        int c = s >> 1, h = s & 1;
        int m = l & 15, cg = l >> 4;
        int co = h * 16 + m;
#pragma unroll
        for (int j = 0; j < 8; j++) {
            int k = c * 32 + cg * 8 + j;
            float v = 0.f;
            if (k < 36) {
                int t = k >> 2, ci = k & 3;
                v = w1[(co * 4 + ci) * 9 + t];
            }
            w1a[i * 8 + j] = (_Float16)v;
        }
    }
    for (int idx = tid; idx < 576; idx += 256) {           // conv2 B-frags (h only)
        int t = idx >> 6, l = idx & 63;
        int co = l & 15, cg = l >> 4;
#pragma unroll
        for (int j = 0; j < 8; j++) {
            int ci = cg * 8 + j;
            w2bh[idx * 8 + j] = (_Float16)w2[(co * 32 + ci) * 9 + t];
        }
    }
    for (int idx = tid; idx < 384; idx += 256) {           // conv3 B-frags: 6 sets (ky,grp) h-only
        int t = idx >> 6, l = idx & 63;
        int ky = t / 2, grp = t & 1;
        int co = l & 15, bq = l >> 4;
#pragma unroll
        for (int j = 0; j < 8; j++) {
            int k = bq * 8 + j;
            float v = 0.f;
            if (co < 8) {
                if (grp == 0) {
                    int kxp = k >> 4, ci = k & 15;
                    v = w3[((co * 16 + ci) * 3 + ky) * 3 + kxp];
                } else if (k < 16) {
                    v = w3[((co * 16 + k) * 3 + ky) * 3 + 2];
                }
            }
            w3f[idx * 8 + j] = (_Float16)v;
        }
    }
}

// ---------------- fused conv1+conv2, f16 h-only MFMA ----------------
// v14: packed-f16 epilogues (pkrtz + pk_leaky + masked AND), else round-11 proven.
__global__ __launch_bounds__(256, 5) void conv12_mfma(const float* __restrict__ x,
                                                      const _Float16* __restrict__ w1a,
                                                      const float* __restrict__ b1,
                                                      const _Float16* __restrict__ wbh,
                                                      const float* __restrict__ b2,
                                                      _Float16* __restrict__ f2n,
                                                      size_t f2n_bstride, int batch0) {
    __shared__ __align__(16) char smem[30656];
    char* f1t = smem;                                  // 10*34*80 = 27200 B (h-only)
    unsigned* xp = (unsigned*)(smem + 27200);          // 2 planes x [12][36] u32 packed f16 pairs
    int tid = threadIdx.x;
    int lane = tid & 63;
    int wid = tid >> 6;
    int bx = blockIdx.x * 32, by = blockIdx.y * 8;
    int n = lane & 15, cg = lane >> 4;
    int m = lane & 15, b = lane >> 4;
    const float* xb = x + (size_t)(batch0 + blockIdx.z) * 4 * HW;
    _Float16* f2nb = f2n + (size_t)blockIdx.z * f2n_bstride;

    // phase 1: stage x halo (rows by-2..by+9, cols bx-2..bx+33) as packed f16 channel pairs
    {
        int idx = tid;
        int r = tid / 36, c = tid - r * 36, plane = 0;
#pragma unroll
        for (int it = 0; it < 4; ++it) {
            if (idx < 864) {
                int gy = by + r - 2, gx = bx + c - 2;
                float v0 = 0.f, v1 = 0.f;
                if ((unsigned)gy < H && (unsigned)gx < W) {
                    const float* pp = xb + (size_t)(2 * plane) * HW + gy * W + gx;
                    v0 = pp[0];
                    v1 = pp[HW];
                }
                xp[idx] = __builtin_bit_cast(unsigned, pkrtz(v0, v1));
            }
            idx += 256;
            c += 4; if (c >= 36) { c -= 36; r += 1; }
            r += 7; if (r >= 12) { r -= 12; plane += 1; }
        }
    }

    half8 Wf00 = *(const half8*)(w1a + (0 * 64 + lane) * 8);
    half8 Wf01 = *(const half8*)(w1a + (1 * 64 + lane) * 8);
    half8 Wf10 = *(const half8*)(w1a + (2 * 64 + lane) * 8);
    half8 Wf11 = *(const half8*)(w1a + (3 * 64 + lane) * 8);
    float bias1[8];
#pragma unroll
    for (int h = 0; h < 2; h++)
#pragma unroll
        for (int j = 0; j < 4; j++)
            bias1[h * 4 + j] = b1[h * 16 + cg * 4 + j];
    half8 Bh[9];
#pragma unroll
    for (int t = 0; t < 9; t++)
        Bh[t] = *(const half8*)(wbh + (t * 64 + lane) * 8);
    f32x4 binit;
#pragma unroll
    for (int j = 0; j < 4; j++) binit[j] = b2[b * 4 + j];

    int t0 = 2 * cg, t1 = 2 * cg + 1;
    int dy0 = (t0 * 11) >> 5, dx0 = t0 - 3 * dy0;
    int dy1 = (t1 * 11) >> 5, dx1 = t1 - 3 * dy1;
    int off0 = dy0 * 36 + dx0, off1 = dy1 * 36 + dx1;
    __syncthreads();

    // phase 2: conv1 via MFMA; 22 tiles of 16 px cover the 340-px halo
#pragma unroll 1
    for (int tt = wid; tt < 22; tt += 4) {
        int p = tt * 16 + n;
        bool valid = p < 340;
        int pc = valid ? p : 339;
        int ry = pc / 34, cx = pc - ry * 34;
        int gy = by + ry - 1, gx = bx + cx - 1;
        bool ok = ((unsigned)gy < H) && ((unsigned)gx < W);
        int base = ry * 36 + cx;
        uint4v uv;
        uv.x = xp[base + off0];
        uv.y = xp[432 + base + off0];
        uv.z = xp[base + off1];
        uv.w = xp[432 + base + off1];
        half8 Xh0 = __builtin_bit_cast(half8, uv);
        half8 Xh1 = {0, 0, 0, 0, 0, 0, 0, 0};
        if (cg == 0) {
            uint4v uw = {0, 0, 0, 0};
            uw.x = xp[base + 74];                      // tap 8 (dy=2,dx=2), ch0|ch1
            uw.y = xp[432 + base + 74];                // ch2|ch3
            Xh1 = __builtin_bit_cast(half8, uw);
        }
        f32x4 d0, d1;
#pragma unroll
        for (int j = 0; j < 4; j++) { d0[j] = bias1[j]; d1[j] = bias1[4 + j]; }
        d0 = __builtin_amdgcn_mfma_f32_16x16x32_f16(Wf00, Xh0, d0, 0, 0, 0);
        d0 = __builtin_amdgcn_mfma_f32_16x16x32_f16(Wf10, Xh1, d0, 0, 0, 0);
        d1 = __builtin_amdgcn_mfma_f32_16x16x32_f16(Wf01, Xh0, d1, 0, 0, 0);
        d1 = __builtin_amdgcn_mfma_f32_16x16x32_f16(Wf11, Xh1, d1, 0, 0, 0);
        if (valid) {
            char* pxb = f1t + ry * 2720 + cx * 80;
            unsigned msk = ok ? 0xFFFFFFFFu : 0u;
#pragma unroll
            for (int h = 0; h < 2; h++) {
                f32x4 d = h ? d1 : d0;
                h2 p0 = pk_leaky(pkrtz(d[0], d[1]));
                h2 p1 = pk_leaky(pkrtz(d[2], d[3]));
                uint2v u;
                u.x = __builtin_bit_cast(unsigned, p0) & msk;
                u.y = __builtin_bit_cast(unsigned, p1) & msk;
                *(uint2v*)(pxb + (h * 4 + cg) * 8) = u;
            }
        }
    }
    __syncthreads();

    // phase 3: conv2 via rolling-row f16 MFMA, D = W*X (lane owns px, 4 co)
    int wx = wid & 1, wy = wid >> 1;
    f32x4 acc2[4];
#pragma unroll
    for (int r = 0; r < 4; r++) acc2[r] = binit;
#pragma unroll
    for (int iy = 0; iy < 6; iy++) {
        int f1row = wy * 4 + iy;
        half8 ah[3];
#pragma unroll
        for (int kx = 0; kx < 3; kx++) {
            int pxi = wx * 16 + m + kx;
            ah[kx] = *(const half8*)(f1t + f1row * 2720 + pxi * 80 + b * 16);
        }
#pragma unroll
        for (int kx = 0; kx < 3; kx++) {
#pragma unroll
            for (int ry = 0; ry < 4; ry++) {
                if (ry >= iy - 2 && ry <= iy) {
                    const int t = (iy - ry) * 3 + kx;
                    acc2[ry] = __builtin_amdgcn_mfma_f32_16x16x32_f16(Bh[t], ah[kx], acc2[ry], 0, 0, 0);
                }
            }
        }
    }

    // epilogue (h-only f2n): pkrtz -> pk leaky -> direct store, 32B/px
    int x0 = bx + wx * 16 + m;
    int y0 = by + wy * 4;
    int co_off = b * 4;
#pragma unroll
    for (int ry = 0; ry < 4; ry++) {
        h2 p0 = pk_leaky(pkrtz(acc2[ry][0], acc2[ry][1]));
        h2 p1 = pk_leaky(pkrtz(acc2[ry][2], acc2[ry][3]));
        uint2v u;
        u.x = __builtin_bit_cast(unsigned, p0);
        u.y = __builtin_bit_cast(unsigned, p1);
        *(uint2v*)(f2nb + ((size_t)(y0 + ry) * W + x0) * 16 + co_off) = u;
    }
}

// ---------------- conv3: h-only f16 MFMA, 32x8 tile, f16 output ----------------
__global__ __launch_bounds__(256) void conv3_mfma(const _Float16* __restrict__ f2n,
                                                  size_t f2n_bstride, int batch0,
                                                  const _Float16* __restrict__ w3f,
                                                  const float* __restrict__ bias,
                                                  _Float16* __restrict__ f3all) {
    __shared__ __align__(16) char st[10 * 34 * 40];    // 13600 B
    int tid = threadIdx.x;
    int lane = tid & 63;
    int wid = tid >> 6;
    int bx = blockIdx.x * 32, by = blockIdx.y * 8;
    const _Float16* f2nb = f2n + (size_t)blockIdx.z * f2n_bstride;
    _Float16* f3 = f3all + (size_t)(batch0 + blockIdx.z) * 8 * HW;

    // stage: rows by-1..by+8, px bx-1..bx+32, 2 x 16B chunks per px (680 tasks)
    for (int idx = tid; idx < 680; idx += 256) {
        int c0 = idx & 1;
        int rp = idx >> 1;
        int r = rp / 34, p = rp - r * 34;
        int gy = by + r - 1, gx = bx + p - 1;
        half8 v = {0, 0, 0, 0, 0, 0, 0, 0};
        if ((unsigned)gy < H && (unsigned)gx < W)
            v = *(const half8*)(f2nb + ((size_t)gy * W + gx) * 16 + c0 * 8);
        *(half8*)(st + r * 1360 + p * 40 + c0 * 16) = v;
    }

    half8 F0[3], F1[3];                                // per ky: grp0-h, grp1-h
#pragma unroll
    for (int ky = 0; ky < 3; ky++) {
        F0[ky] = *(const half8*)(w3f + ((ky * 2 + 0) * 64 + lane) * 8);
        F1[ky] = *(const half8*)(w3f + ((ky * 2 + 1) * 64 + lane) * 8);
    }
    int m = lane & 15, b = lane >> 4;
    int halfco = b & 1, kxp = b >> 1;
    int wx = wid & 1, wy = wid >> 1;
    float bc = (m < 8) ? bias[m] : 0.f;
    f32x4 acc[4];
#pragma unroll
    for (int r = 0; r < 4; r++) acc[r] = (f32x4){bc, bc, bc, bc};
    int pA = wx * 16 + m + kxp;                        // halo-local px for A (kx -1,0)
    int pB = wx * 16 + m + 2;                          // halo-local px for B (kx +1)
    __syncthreads();

#pragma unroll
    for (int iy = 0; iy < 6; iy++) {
        const char* rp = st + (wy * 4 + iy) * 1360;
        half8 ka_h = *(const half8*)(rp + pA * 40 + halfco * 16);
        half8 kb_h = *(const half8*)(rp + pB * 40 + halfco * 16);
#pragma unroll
        for (int ry = 0; ry < 4; ry++) {
            if (ry >= iy - 2 && ry <= iy) {
                const int ky = iy - ry;
                acc[ry] = __builtin_amdgcn_mfma_f32_16x16x32_f16(ka_h, F0[ky], acc[ry], 0, 0, 0);
                acc[ry] = __builtin_amdgcn_mfma_f32_16x16x32_f16(kb_h, F1[ky], acc[ry], 0, 0, 0);
            }
        }
    }

    if (m < 8) {
#pragma unroll
        for (int ry = 0; ry < 4; ry++) {
            int y = by + wy * 4 + ry;
            h2 p0 = pkrtz(acc[ry][0], acc[ry][1]);
            h2 p1 = pkrtz(acc[ry][2], acc[ry][3]);
            uint2v u;
            u.x = __builtin_bit_cast(unsigned, p0);
            u.y = __builtin_bit_cast(unsigned, p1);
            *(uint2v*)(f3 + (size_t)m * HW + (size_t)y * W + bx + wx * 16 + b * 4) = u;
        }
    }
}

// ---------------- stdfuse v9: v8 + packed-f16 phase-3 finishing ----------------
__global__ __launch_bounds__(256) void stdfuse_fused(const _Float16* __restrict__ f3all,
                                                     const float* __restrict__ fw,
                                                     const float* __restrict__ fb,
                                                     const float* __restrict__ stats,
                                                     float* __restrict__ out) {
    __shared__ __align__(16) _Float16 raw[46 * 50];
    __shared__ __align__(16) _Float16 hsqh[3][46 * 68];
    __shared__ int rowOff[46];      // reflected gy * W (element offset)
    __shared__ int gxcol[46];       // reflected gx
    int tid = threadIdx.x;
    int xq = tid & 15, yp = tid >> 4;
    int bx = blockIdx.x * 32, by = blockIdx.y * 32;
    int batch = blockIdx.z;
    const _Float16* f3 = f3all + (size_t)batch * 8 * HW;

    if (tid < 46) {
        int gy = by + tid - 7;
        gy = gy < 0 ? -gy : (gy > 1023 ? 2046 - gy : gy);
        rowOff[tid] = gy * W;
        int gx = bx + tid - 7;
        gx = gx < 0 ? -gx : (gx > 1023 ? 2046 - gx : gx);
        gxcol[tid] = gx;
    }
    __syncthreads();

    // per-thread staging task table (channel-invariant): 2116 = 8*256 + 68 tasks
    int goffB[9];   // global byte offset within a channel plane (f16)
    int laddB[9];   // LDS byte offset into raw (f16)
    const bool k8 = tid < 68;
#pragma unroll
    for (int k = 0; k < 9; k++) {
        int idx = tid + k * 256;
        int idc = idx < 2116 ? idx : 2115;
        int r = idc / 46, c = idc - r * 46;
        goffB[k] = (rowOff[r] + gxcol[c]) * 2;
        laddB[k] = (r * 50 + c) * 2;
    }

    float wwin[3] = {fw[0] * 0.125f, fw[1] * 0.125f, fw[2] * 0.125f};
    float part[4] = {0.f, 0.f, 0.f, 0.f};

    // prologue: load channel 0 into registers (raw f16 bits, no conversion)
    unsigned short stg[9];
    {
        const char* src = (const char*)f3;
#pragma unroll
        for (int k = 0; k < 8; k++) stg[k] = *(const unsigned short*)(src + goffB[k]);
        stg[8] = k8 ? *(const unsigned short*)(src + goffB[8]) : (unsigned short)0;
    }

    for (int z = 0; z < 8; z++) {
        // write staged registers to raw (safe: prior phase-2 raw reads ended at barrier B)
        char* rb = (char*)raw;
#pragma unroll
        for (int k = 0; k < 8; k++) *(unsigned short*)(rb + laddB[k]) = stg[k];
        if (k8) *(unsigned short*)(rb + laddB[8]) = stg[8];

        // T14: issue next channel's loads BEFORE the barrier; latency hides under phase 2+3
        if (z < 7) {
            const char* nsrc = (const char*)(f3 + (size_t)(z + 1) * HW);
#pragma unroll
            for (int k = 0; k < 8; k++) stg[k] = *(const unsigned short*)(nsrc + goffB[k]);
            if (k8) stg[8] = *(const unsigned short*)(nsrc + goffB[8]);
        }
        __syncthreads();   // A: raw ready; prior phase-3 hsqh reads complete

        // phase 2: A/B-pair packed horizontal window sums -> half4 {sA,sB,qA,qB}
        for (int idx = tid; idx < 736; idx += 256) {
            int r = idx >> 4, xh = idx & 15;
            const unsigned* rp = (const unsigned*)raw + r * 25 + xh;
            unsigned d[8];
#pragma unroll
            for (int i = 0; i < 8; i++) d[i] = rp[i];
            h2 vp[15];
#pragma unroll
            for (int i = 0; i < 8; i++)
                if (2 * i < 15) vp[2 * i] = __builtin_bit_cast(h2, d[i]);
#pragma unroll
            for (int i = 0; i < 7; i++)
                vp[2 * i + 1] = __builtin_bit_cast(h2, __builtin_amdgcn_alignbit(d[i + 1], d[i], 16));
            h2 wp[15];
#pragma unroll
            for (int k = 0; k < 15; k++) wp[k] = vp[k] * vp[k];
            h2 s5 = vp[5] + vp[6] + vp[7] + vp[8] + vp[9];
            h2 q5 = wp[5] + wp[6] + wp[7] + wp[8] + wp[9];
            h2 s9 = s5 + vp[3] + vp[4] + vp[10] + vp[11];
            h2 q9 = q5 + wp[3] + wp[4] + wp[10] + wp[11];
            h2 s15 = s9 + vp[0] + vp[1] + vp[2] + vp[12] + vp[13] + vp[14];
            h2 q15 = q9 + wp[0] + wp[1] + wp[2] + wp[12] + wp[13] + wp[14];
            int ho = r * 68 + 4 * xh;
            uint2v u0, u1, u2;
            u0.x = __builtin_bit_cast(unsigned, s5);
            u0.y = __builtin_bit_cast(unsigned, q5);
            u1.x = __builtin_bit_cast(unsigned, s9);
            u1.y = __builtin_bit_cast(unsigned, q9);
            u2.x = __builtin_bit_cast(unsigned, s15);
            u2.y = __builtin_bit_cast(unsigned, q15);
            *(uint2v*)&hsqh[0][ho] = u0;
            *(uint2v*)&hsqh[1][ho] = u1;
            *(uint2v*)&hsqh[2][ho] = u2;
        }
        __syncthreads();   // B: hsqh ready; all raw reads complete

        // phase 3: vertical sums (packed) + packed m/var finishing, f32 only for sqrt
#pragma unroll
        for (int wi = 0; wi < 3; wi++) {
            const int wlen = (wi == 0) ? 5 : ((wi == 1) ? 9 : 15);
            const int r0 = 2 * yp + 7 - (wlen >> 1);
            const float inv = 1.0f / (float)(wlen * wlen);
            const float ww = wwin[wi];
            const _Float16* basep = &hsqh[wi][4 * xq];
            half4 first = *(const half4*)(basep + r0 * 68);
            half4 e = first;
            half4 o = *(const half4*)(basep + (r0 + 1) * 68);
#pragma unroll
            for (int k = 2; k + 1 < wlen; k += 2) {
                e += *(const half4*)(basep + (r0 + k) * 68);
                o += *(const half4*)(basep + (r0 + k + 1) * 68);
            }
            e += *(const half4*)(basep + (r0 + wlen - 1) * 68);   // last even row
            half4 tot = e + o;
            half4 last = *(const half4*)(basep + (r0 + wlen) * 68);
            half4 sh = tot - first + last;
            // layout: [0]=sA [1]=sB [2]=qA [3]=qB
            uint2v ut = __builtin_bit_cast(uint2v, tot);
            uint2v us = __builtin_bit_cast(uint2v, sh);
            h2 s0 = __builtin_bit_cast(h2, ut.x), q0 = __builtin_bit_cast(h2, ut.y);
            h2 s1 = __builtin_bit_cast(h2, us.x), q1 = __builtin_bit_cast(h2, us.y);
            h2 invh = {(_Float16)inv, (_Float16)inv};
            h2 m0 = s0 * invh, m20 = q0 * invh;
            h2 m1 = s1 * invh, m21 = q1 * invh;
            h2 var0 = m20 - m0 * m0;
            h2 var1 = m21 - m1 * m1;
            part[0] += ww * fast_sqrtf(fmaxf((float)var0[0], 0.f) + 1e-8f);
            part[1] += ww * fast_sqrtf(fmaxf((float)var0[1], 0.f) + 1e-8f);
            part[2] += ww * fast_sqrtf(fmaxf((float)var1[0], 0.f) + 1e-8f);
            part[3] += ww * fast_sqrtf(fmaxf((float)var1[1], 0.f) + 1e-8f);
        }
        // no barrier: next iter writes raw (disjoint from hsqh); hsqh rewritten only after next barrier A
    }

    // epilogue: fused value -> per-channel threshold + sigmoid, direct output write
    float fb0 = fb[0];
    int gy = by + 2 * yp, gx = bx + 2 * xq;
#pragma unroll
    for (int c = 0; c < 4; c++) {
        float lo = stats[(batch * 4 + c) * 2];
        float up = stats[(batch * 4 + c) * 2 + 1];
        float inv = 1.f / (up - lo);
        float v[4];
#pragma unroll
        for (int p = 0; p < 4; p++) {
            float ns = (part[p] + fb0 - lo) * inv;
            ns = fminf(fmaxf(ns, 0.f), 1.f);
            v[p] = 1.f / (1.f + fast_expf(3.f - 6.f * ns));
        }
        float* plane = out + ((size_t)(batch * 4 + c)) * HW;
        *(float2*)(plane + (size_t)gy * W + gx) = make_float2(v[0], v[1]);
        *(float2*)(plane + (size_t)(gy + 1) * W + gx) = make_float2(v[2], v[3]);
    }
}

extern "C" void kernel_launch(void* const* d_in, const int* in_sizes, int n_in,
                              void* d_out, int out_size, void* d_ws, size_t ws_size,
                              hipStream_t stream) {
    (void)in_sizes; (void)n_in; (void)out_size;
    const float* x = (const float*)d_in[0];
    const float* w1 = (const float*)d_in[1];
    const float* b1 = (const float*)d_in[2];
    const float* w2 = (const float*)d_in[3];
    const float* b2 = (const float*)d_in[4];
    const float* w3 = (const float*)d_in[5];
    const float* b3 = (const float*)d_in[6];
    const float* chw = (const float*)d_in[7];
    const float* fw = (const float*)d_in[8];
    const float* fb = (const float*)d_in[9];
    float* out = (float*)d_out;

    char* ws = (char*)d_ws;
    float* stats = (float*)ws;                         // 32 f
    double* part = (double*)(ws + 256);                // 1024 d, ends 8448
    _Float16* w1a = (_Float16*)(ws + 8448);            // 2048 f16, ends 12544
    _Float16* w3f = (_Float16*)(ws + 24832);           // 3072 f16, ends 30976
    _Float16* w2bh = (_Float16*)(ws + 37120);          // 4608 f16, ends 46336
    _Float16* f3all = (_Float16*)(ws + 65536);         // 4 batches x 8 ch x HW f16 = 64 MB
    _Float16* f2n = (_Float16*)(ws + 67174400);        // h-only planes of 32 MB

    // wide mode: 4 f2n planes -> single conv12 + single conv3 dispatch (needs 192.05 MB ws)
    const size_t PLANE = (size_t)16 * HW;              // f16 elements per f2n plane
    const size_t WIDE_WS = 67174400ULL + 4ULL * PLANE * sizeof(_Float16);
    bool wide = ws_size >= WIDE_WS;

    stats_partial<<<512, 256, 0, stream>>>(x, part);
    stats_final_prep<<<1, 256, 0, stream>>>(part, chw, w1, w2, w3, stats, w1a, w3f, w2bh);

    if (wide) {
        conv12_mfma<<<dim3(32, 128, 4), 256, 0, stream>>>(x, w1a, b1, w2bh, b2, f2n, PLANE, 0);
        conv3_mfma<<<dim3(32, 128, 4), 256, 0, stream>>>(f2n, PLANE, 0, w3f, b3, f3all);
    } else {
        for (int b = 0; b < 4; b++) {
            conv12_mfma<<<dim3(32, 128, 1), 256, 0, stream>>>(x, w1a, b1, w2bh, b2, f2n, 0, b);
            conv3_mfma<<<dim3(32, 128, 1), 256, 0, stream>>>(f2n, 0, b, w3f, b3, f3all);
        }
    }
    stdfuse_fused<<<dim3(32, 32, 4), 256, 0, stream>>>(f3all, fw, fb, stats, out);
}